// Round 5
// baseline (349.156 us; speedup 1.0000x reference)
//
#include <hip/hip_runtime.h>
#include <math.h>

#define R2 2500.0f
#define EPSF 1e-8f

constexpr int H   = 256;   // feature dim (fixed by problem)
constexpr int HH  = 128;   // hidden dim
constexpr int NB  = 8;     // col-buckets per row (bucket = col>>11 -> 2048 nodes = 2MB of x)
constexpr int BSH = 11;    // bucket shift
constexpr int RPW = 4;     // rows per wave in k_fvar (R4's 8 -> 4: 2x TLP, same locality)

// ---------------- K1: degree count per (row, bucket) ----------------
__global__ void k_degree(const int* __restrict__ row, const int* __restrict__ col,
                         int* __restrict__ deg4, int E) {
    int e = blockIdx.x * blockDim.x + threadIdx.x;
    if (e < E) atomicAdd(&deg4[row[e] * NB + (col[e] >> BSH)], 1);
}

// ---------------- K2: parallel exclusive scan over M=N*NB ----------------
__global__ void __launch_bounds__(256) k_bsum(const int* __restrict__ deg4,
                                              int* __restrict__ bsum) {
    int t = threadIdx.x;
    int4 v = ((const int4*)deg4)[blockIdx.x * 256 + t];
    int sum = v.x + v.y + v.z + v.w;
#pragma unroll
    for (int off = 32; off > 0; off >>= 1) sum += __shfl_xor(sum, off, 64);
    __shared__ int sw[4];
    if ((t & 63) == 0) sw[t >> 6] = sum;
    __syncthreads();
    if (t == 0) bsum[blockIdx.x] = sw[0] + sw[1] + sw[2] + sw[3];
}

__global__ void k_bscan(const int* __restrict__ bsum, int* __restrict__ boff) {
    __shared__ int s[128];
    int t = threadIdx.x;
    s[t] = bsum[t];
    __syncthreads();
    for (int off = 1; off < 128; off <<= 1) {
        int v = s[t];
        int add = (t >= off) ? s[t - off] : 0;
        __syncthreads();
        s[t] = v + add;
        __syncthreads();
    }
    boff[t] = (t > 0) ? s[t - 1] : 0;
}

__global__ void __launch_bounds__(256) k_scat(const int* __restrict__ deg4,
                                              const int* __restrict__ boff,
                                              int* __restrict__ rp4,
                                              int* __restrict__ cur4, int M) {
    int t = threadIdx.x, blk = blockIdx.x;
    int lane = t & 63, w = t >> 6;
    int4 v = ((const int4*)deg4)[blk * 256 + t];
    int tsum = v.x + v.y + v.z + v.w;
    int incl = tsum;
#pragma unroll
    for (int off = 1; off < 64; off <<= 1) {
        int n = __shfl_up(incl, off, 64);
        if (lane >= off) incl += n;
    }
    __shared__ int wsum[4];
    if (lane == 63) wsum[w] = incl;
    __syncthreads();
    int woff = 0;
#pragma unroll
    for (int k = 0; k < 4; k++) woff += (k < w) ? wsum[k] : 0;
    int excl = boff[blk] + woff + (incl - tsum);
    int4 r;
    r.x = excl;
    r.y = excl + v.x;
    r.z = excl + v.x + v.y;
    r.w = excl + v.x + v.y + v.z;
    ((int4*)rp4)[blk * 256 + t]  = r;
    ((int4*)cur4)[blk * 256 + t] = r;
    if (blk == gridDim.x - 1 && t == 255) rp4[M] = excl + tsum;
}

// ---------------- K3: fill bucket-sorted CSR ----------------
__global__ void k_fill(const int* __restrict__ row, const int* __restrict__ col,
                       int* __restrict__ cur4, int* __restrict__ cols, int E) {
    int e = blockIdx.x * blockDim.x + threadIdx.x;
    if (e < E) {
        int r = row[e], c = col[e];
        int p = atomicAdd(&cur4[r * NB + (c >> BSH)], 1);
        cols[p] = c;
    }
}

// ---------------- K4: spatial density via 20x20 cell grid ----------------
// Radius=50 == cell width; evaluating the 5x5 (+-2 cell) neighborhood with the
// EXACT same d2 expression as the previous full sweep gives a bitwise-identical
// count: excluded pairs have coordinate gap > 100 -> true d2 > ~9999, far
// beyond fp round-off of the (sq+sq)-2dot contraction (~1), so no borderline
// (d2<=2500) pair can be missed. Integer count -> enumeration order irrelevant.
__global__ void k_cellcnt(const float* __restrict__ coords, int* __restrict__ cellcnt, int N) {
    int t = blockIdx.x * 256 + threadIdx.x;
    float2 c = ((const float2*)coords)[t];
    int cx = (int)(c.x * 0.02f); if (cx > 19) cx = 19;
    int cy = (int)(c.y * 0.02f); if (cy > 19) cy = 19;
    atomicAdd(&cellcnt[cy * 20 + cx], 1);
}

__global__ void k_cellscan(const int* __restrict__ cellcnt, int* __restrict__ cellstart,
                           int* __restrict__ cellcur) {
    __shared__ int s[512];
    int t = threadIdx.x;
    s[t] = (t < 400) ? cellcnt[t] : 0;
    __syncthreads();
    for (int off = 1; off < 512; off <<= 1) {
        int v = s[t];
        int add = (t >= off) ? s[t - off] : 0;
        __syncthreads();
        s[t] = v + add;
        __syncthreads();
    }
    if (t < 400) {
        int excl = (t > 0) ? s[t - 1] : 0;
        cellstart[t] = excl;
        cellcur[t]   = excl;
    }
    if (t == 400) cellstart[400] = s[399];
}

__global__ void k_cellfill(const float* __restrict__ coords, int* __restrict__ cellcur,
                           float4* __restrict__ pts, int N) {
    int t = blockIdx.x * 256 + threadIdx.x;
    float2 c = ((const float2*)coords)[t];
    int cx = (int)(c.x * 0.02f); if (cx > 19) cx = 19;
    int cy = (int)(c.y * 0.02f); if (cy > 19) cy = 19;
    int p = atomicAdd(&cellcur[cy * 20 + cx], 1);
    pts[p] = make_float4(c.x, c.y, c.x * c.x + c.y * c.y, __int_as_float(t));
}

__global__ void __launch_bounds__(256) k_dgrid(
    const float4* __restrict__ pts, const int* __restrict__ cellstart,
    int* __restrict__ dens, int N) {
    int t = blockIdx.x * 256 + threadIdx.x;   // cell-sorted order: wave-local window reuse
    float4 p = pts[t];
    int cx = (int)(p.x * 0.02f); if (cx > 19) cx = 19;
    int cy = (int)(p.y * 0.02f); if (cy > 19) cy = 19;
    int x0 = cx - 2; if (x0 < 0) x0 = 0;
    int x1 = cx + 2; if (x1 > 19) x1 = 19;
    int y0 = cy - 2; if (y0 < 0) y0 = 0;
    int y1 = cy + 2; if (y1 > 19) y1 = 19;
    int cnt = 0;
    for (int yy = y0; yy <= y1; yy++) {
        int rowb = yy * 20;
        int s = cellstart[rowb + x0];
        int e = cellstart[rowb + x1 + 1];   // cells in a row are contiguous in pts
        for (int q = s; q < e; q++) {
            float4 pq = pts[q];
            float dot = p.x * pq.x + p.y * pq.y;
            float d2 = (p.z + pq.z) - 2.0f * dot;
            cnt += (d2 <= R2) ? 1 : 0;
        }
    }
    dens[__float_as_int(p.w)] = cnt;
}

// ---------------- K5: fvar — bucket-major synchronized sweep ----------------
// RPW=4: grid = N/16 = 1024 blocks = 4/CU (LDS 32KB -> up to 5 resident, so
// all blocks co-resident from t=0; phase-synced bucket sweep keeps the 2MB
// window L2-resident). 16 waves/CU = 2x R4's TLP to overlap per-segment
// drain stalls (segments avg 4 edges -> latency-bound, not BW-bound).
__global__ void __launch_bounds__(256) k_fvar(
    const float* __restrict__ x, const int* __restrict__ rp4,
    const int* __restrict__ cols, float* __restrict__ fvar, int N) {
    __shared__ float4 lds[4][8][64];   // 4 waves x 8 slots x 1KB = 32KB
    int wave = threadIdx.x >> 6;
    int lane = threadIdx.x & 63;
    int i0 = (blockIdx.x * 4 + wave) * RPW;
    const float4* xb = (const float4*)x;   // 64 float4 per row
    float4 acc[RPW];
#pragma unroll
    for (int r = 0; r < RPW; r++) acc[r] = make_float4(0.f, 0.f, 0.f, 0.f);

    for (int b = 0; b < NB; b++) {
#pragma unroll
        for (int r = 0; r < RPW; r++) {
            int s = rp4[(i0 + r) * NB + b];
            int e = rp4[(i0 + r) * NB + b + 1];
            for (int p0 = s; p0 < e; p0 += 64) {
                int m = e - p0; if (m > 64) m = 64;
                int idx = cols[p0 + (lane < m ? lane : m - 1)];
                for (int j = 0; j < m; j += 8) {
                    int nb2 = m - j; if (nb2 > 8) nb2 = 8;
#pragma unroll
                    for (int k = 0; k < 8; k++) {
                        if (k < nb2) {
                            int c = __shfl(idx, j + k, 64);
                            const float4* gp = xb + (size_t)c * 64 + lane;
                            __builtin_amdgcn_global_load_lds(
                                (const __attribute__((address_space(1))) void*)gp,
                                (__attribute__((address_space(3))) void*)(&lds[wave][k][0]),
                                16, 0, 0);
                        }
                    }
                    __builtin_amdgcn_s_waitcnt(0);   // drain the async row fetches
#pragma unroll
                    for (int k = 0; k < 8; k++) {
                        if (k < nb2) {
                            float4 v = lds[wave][k][lane];
                            acc[r].x += v.x; acc[r].y += v.y;
                            acc[r].z += v.z; acc[r].w += v.w;
                        }
                    }
                }
            }
        }
    }

#pragma unroll
    for (int r = 0; r < RPW; r++) {
        int i = i0 + r;
        float cnt = fmaxf((float)(rp4[(i + 1) * NB] - rp4[i * NB]), 1.0f);
        float4 xi = xb[(size_t)i * 64 + lane];
        float dx = xi.x - acc[r].x / cnt;
        float dy = xi.y - acc[r].y / cnt;
        float dz = xi.z - acc[r].z / cnt;
        float dw = xi.w - acc[r].w / cnt;
        float ss = dx * dx + dy * dy + dz * dz + dw * dw;
#pragma unroll
        for (int off = 32; off > 0; off >>= 1) ss += __shfl_xor(ss, off, 64);
        if (lane == 0) fvar[i] = sqrtf(ss);
    }
}

// ---------------- K5b: maxima reduction (deg, dens, fvar) ----------------
__global__ void __launch_bounds__(256) k_scal(
    const int* __restrict__ rp4, const int* __restrict__ dens,
    const float* __restrict__ fvar, int* __restrict__ scal, int N) {
    __shared__ int sd[4], sn[4];
    __shared__ float sf[4];
    int t = threadIdx.x;
    int g = blockIdx.x * 256 + t;
    int stride = 256 * gridDim.x;
    int md = 0, mn = 0;
    float mf = 0.f;
    for (int i = g; i < N; i += stride) {
        md = max(md, rp4[(i + 1) * NB] - rp4[i * NB]);
        mn = max(mn, dens[i]);
        mf = fmaxf(mf, fvar[i]);
    }
#pragma unroll
    for (int off = 32; off > 0; off >>= 1) {
        md = max(md, __shfl_xor(md, off, 64));
        mn = max(mn, __shfl_xor(mn, off, 64));
        mf = fmaxf(mf, __shfl_xor(mf, off, 64));
    }
    int w = t >> 6, l = t & 63;
    if (l == 0) { sd[w] = md; sn[w] = mn; sf[w] = mf; }
    __syncthreads();
    if (t == 0) {
#pragma unroll
        for (int k = 1; k < 4; k++) {
            md = max(md, sd[k]);
            mn = max(mn, sn[k]);
            mf = fmaxf(mf, sf[k]);
        }
        atomicMax(&scal[0], md);
        atomicMax(&scal[1], mn);
        atomicMax(&scal[2], __float_as_int(mf));   // nonneg float: int-max ok
    }
}

// ---------------- K6: tiny MLP ----------------
__global__ void __launch_bounds__(256) k_mlp(
    const float* __restrict__ w1, const float* __restrict__ b1,
    const float* __restrict__ w2, const float* __restrict__ b2,
    const int* __restrict__ rp4, const int* __restrict__ dens,
    const float* __restrict__ fvar, const int* __restrict__ scal,
    float* __restrict__ out, int N) {
    __shared__ float sh_h[HH];
    int j = threadIdx.x;
    float wv[HH];
#pragma unroll
    for (int l = 0; l < HH; l++) wv[l] = w2[l * H + j];
    float bj = b2[j];
    float maxdeg  = (float)scal[0] + EPSF;
    float maxdens = (float)(scal[1] - 1) + EPSF;
    float maxfv   = __int_as_float(scal[2]) + EPSF;
    float w1a = 0.f, w1b = 0.f, w1c = 0.f, b1j = 0.f;
    if (j < HH) { w1a = w1[j]; w1b = w1[HH + j]; w1c = w1[2 * HH + j]; b1j = b1[j]; }
    for (int i = blockIdx.x; i < N; i += gridDim.x) {
        float f0 = (float)(rp4[(i + 1) * NB] - rp4[i * NB]) / maxdeg;
        float f1 = (float)(dens[i] - 1) / maxdens;
        float f2 = fvar[i] / maxfv;
        if (j < HH) {
            float h = f0 * w1a + f1 * w1b + f2 * w1c + b1j;
            sh_h[j] = fmaxf(h, 0.0f);
        }
        __syncthreads();
        float acc = bj;
#pragma unroll
        for (int l = 0; l < HH; l++) acc = fmaf(sh_h[l], wv[l], acc);
        out[(size_t)i * H + j] = acc;
        __syncthreads();
    }
}

extern "C" void kernel_launch(void* const* d_in, const int* in_sizes, int n_in,
                              void* d_out, int out_size, void* d_ws, size_t ws_size,
                              hipStream_t stream) {
    const float* x      = (const float*)d_in[0];
    const int*   ei     = (const int*)d_in[1];
    const float* coords = (const float*)d_in[2];
    const float* w1     = (const float*)d_in[3];
    const float* b1     = (const float*)d_in[4];
    const float* w2     = (const float*)d_in[5];
    const float* b2     = (const float*)d_in[6];
    float* out = (float*)d_out;

    const int N = in_sizes[2] / 2;   // 16384
    const int E = in_sizes[1] / 2;   // 524288
    const int M = N * NB;            // 131072
    const int NBLK = M / 1024;       // 128 scan blocks
    const int* row = ei;
    const int* col = ei + E;

    // workspace layout (int32 elements; int4/float4 arrays 16B-aligned)
    int* ws        = (int*)d_ws;
    int* scal      = ws;                       // [4]     zeroed
    int* deg4      = ws + 4;                   // [M]     zeroed  (16B-aligned)
    int* cellcnt   = ws + 4 + M;               // [404]   zeroed  (400 used)
    int* rp4       = ws + 408 + M;             // [M+4]           (16B-aligned)
    int* cur4      = rp4 + M + 4;              // [M]             (16B-aligned)
    int* cellstart = cur4 + M;                 // [404]   (401 used)
    int* cellcur   = cellstart + 404;          // [400]
    int* dens_cnt  = cellcur + 400;            // [N]
    float* fvarp   = (float*)(dens_cnt + N);   // [N]
    int* bsum      = dens_cnt + 2 * N;         // [128]
    int* boff      = bsum + 128;               // [128]
    int* cols      = boff + 128;               // [E]
    float4* pts    = (float4*)(cols + E);      // [N]  (offset 951744 ints: 16B-aligned)

    hipMemsetAsync(ws, 0, (size_t)(408 + M) * sizeof(int), stream);

    int eb = (E + 255) / 256;
    k_degree<<<eb, 256, 0, stream>>>(row, col, deg4, E);
    k_bsum<<<NBLK, 256, 0, stream>>>(deg4, bsum);
    k_bscan<<<1, NBLK, 0, stream>>>(bsum, boff);
    k_scat<<<NBLK, 256, 0, stream>>>(deg4, boff, rp4, cur4, M);
    k_fill<<<eb, 256, 0, stream>>>(row, col, cur4, cols, E);

    k_cellcnt<<<N / 256, 256, 0, stream>>>(coords, cellcnt, N);
    k_cellscan<<<1, 512, 0, stream>>>(cellcnt, cellstart, cellcur);
    k_cellfill<<<N / 256, 256, 0, stream>>>(coords, cellcur, pts, N);
    k_dgrid<<<N / 256, 256, 0, stream>>>(pts, cellstart, dens_cnt, N);

    k_fvar<<<N / (4 * RPW), 256, 0, stream>>>(x, rp4, cols, fvarp, N);

    k_scal<<<64, 256, 0, stream>>>(rp4, dens_cnt, fvarp, scal, N);

    k_mlp<<<1024, 256, 0, stream>>>(w1, b1, w2, b2, rp4, dens_cnt, fvarp, scal,
                                    out, N);
}

// Round 6
// 267.182 us; speedup vs baseline: 1.3068x; 1.3068x over previous
//
#include <hip/hip_runtime.h>
#include <math.h>

#define R2 2500.0f
#define EPSF 1e-8f

constexpr int H   = 256;   // feature dim (fixed by problem)
constexpr int HH  = 128;   // hidden dim
constexpr int NB  = 8;     // col-buckets per row (bucket = col>>11 -> 2048 nodes = 2MB of x)
constexpr int BSH = 11;    // bucket shift
constexpr int RPW = 4;     // rows per wave in k_fvar

// ---------------- K1: degree count per (row, bucket) ----------------
__global__ void k_degree(const int* __restrict__ row, const int* __restrict__ col,
                         int* __restrict__ deg4, int E) {
    int e = blockIdx.x * blockDim.x + threadIdx.x;
    if (e < E) atomicAdd(&deg4[row[e] * NB + (col[e] >> BSH)], 1);
}

// ---------------- K2: parallel exclusive scan over M=N*NB ----------------
__global__ void __launch_bounds__(256) k_bsum(const int* __restrict__ deg4,
                                              int* __restrict__ bsum) {
    int t = threadIdx.x;
    int4 v = ((const int4*)deg4)[blockIdx.x * 256 + t];
    int sum = v.x + v.y + v.z + v.w;
#pragma unroll
    for (int off = 32; off > 0; off >>= 1) sum += __shfl_xor(sum, off, 64);
    __shared__ int sw[4];
    if ((t & 63) == 0) sw[t >> 6] = sum;
    __syncthreads();
    if (t == 0) bsum[blockIdx.x] = sw[0] + sw[1] + sw[2] + sw[3];
}

__global__ void k_bscan(const int* __restrict__ bsum, int* __restrict__ boff) {
    __shared__ int s[128];
    int t = threadIdx.x;
    s[t] = bsum[t];
    __syncthreads();
    for (int off = 1; off < 128; off <<= 1) {
        int v = s[t];
        int add = (t >= off) ? s[t - off] : 0;
        __syncthreads();
        s[t] = v + add;
        __syncthreads();
    }
    boff[t] = (t > 0) ? s[t - 1] : 0;
}

__global__ void __launch_bounds__(256) k_scat(const int* __restrict__ deg4,
                                              const int* __restrict__ boff,
                                              int* __restrict__ rp4,
                                              int* __restrict__ cur4, int M) {
    int t = threadIdx.x, blk = blockIdx.x;
    int lane = t & 63, w = t >> 6;
    int4 v = ((const int4*)deg4)[blk * 256 + t];
    int tsum = v.x + v.y + v.z + v.w;
    int incl = tsum;
#pragma unroll
    for (int off = 1; off < 64; off <<= 1) {
        int n = __shfl_up(incl, off, 64);
        if (lane >= off) incl += n;
    }
    __shared__ int wsum[4];
    if (lane == 63) wsum[w] = incl;
    __syncthreads();
    int woff = 0;
#pragma unroll
    for (int k = 0; k < 4; k++) woff += (k < w) ? wsum[k] : 0;
    int excl = boff[blk] + woff + (incl - tsum);
    int4 r;
    r.x = excl;
    r.y = excl + v.x;
    r.z = excl + v.x + v.y;
    r.w = excl + v.x + v.y + v.z;
    ((int4*)rp4)[blk * 256 + t]  = r;
    ((int4*)cur4)[blk * 256 + t] = r;
    if (blk == gridDim.x - 1 && t == 255) rp4[M] = excl + tsum;
}

// ---------------- K3: fill bucket-sorted CSR ----------------
__global__ void k_fill(const int* __restrict__ row, const int* __restrict__ col,
                       int* __restrict__ cur4, int* __restrict__ cols, int E) {
    int e = blockIdx.x * blockDim.x + threadIdx.x;
    if (e < E) {
        int r = row[e], c = col[e];
        int p = atomicAdd(&cur4[r * NB + (c >> BSH)], 1);
        cols[p] = c;
    }
}

// ---------------- K4: spatial density via 20x20 cell grid ----------------
// Same bitwise-identical pruning as R5 (5x5 neighborhood, same d2 expression,
// integer count). NEW: one WAVE per point (was one thread) — lanes stride the
// neighbor ranges with coalesced float4 loads, shfl_xor count reduction.
// Grid N/4 = 4096 blocks = 16/CU (was 64 blocks = 0.25/CU, the R5 regression).
__global__ void k_cellcnt(const float* __restrict__ coords, int* __restrict__ cellcnt, int N) {
    int t = blockIdx.x * 256 + threadIdx.x;
    float2 c = ((const float2*)coords)[t];
    int cx = (int)(c.x * 0.02f); if (cx > 19) cx = 19;
    int cy = (int)(c.y * 0.02f); if (cy > 19) cy = 19;
    atomicAdd(&cellcnt[cy * 20 + cx], 1);
}

__global__ void k_cellscan(const int* __restrict__ cellcnt, int* __restrict__ cellstart,
                           int* __restrict__ cellcur) {
    __shared__ int s[512];
    int t = threadIdx.x;
    s[t] = (t < 400) ? cellcnt[t] : 0;
    __syncthreads();
    for (int off = 1; off < 512; off <<= 1) {
        int v = s[t];
        int add = (t >= off) ? s[t - off] : 0;
        __syncthreads();
        s[t] = v + add;
        __syncthreads();
    }
    if (t < 400) {
        int excl = (t > 0) ? s[t - 1] : 0;
        cellstart[t] = excl;
        cellcur[t]   = excl;
    }
    if (t == 400) cellstart[400] = s[399];
}

__global__ void k_cellfill(const float* __restrict__ coords, int* __restrict__ cellcur,
                           float4* __restrict__ pts, int N) {
    int t = blockIdx.x * 256 + threadIdx.x;
    float2 c = ((const float2*)coords)[t];
    int cx = (int)(c.x * 0.02f); if (cx > 19) cx = 19;
    int cy = (int)(c.y * 0.02f); if (cy > 19) cy = 19;
    int p = atomicAdd(&cellcur[cy * 20 + cx], 1);
    pts[p] = make_float4(c.x, c.y, c.x * c.x + c.y * c.y, __int_as_float(t));
}

__global__ void __launch_bounds__(256) k_dgrid(
    const float4* __restrict__ pts, const int* __restrict__ cellstart,
    int* __restrict__ dens, int N) {
    int wave = threadIdx.x >> 6;
    int lane = threadIdx.x & 63;
    int t = blockIdx.x * 4 + wave;          // one wave per point
    float4 p = pts[t];
    int cx = (int)(p.x * 0.02f); if (cx > 19) cx = 19;
    int cy = (int)(p.y * 0.02f); if (cy > 19) cy = 19;
    int x0 = cx - 2; if (x0 < 0) x0 = 0;
    int x1 = cx + 2; if (x1 > 19) x1 = 19;
    int y0 = cy - 2; if (y0 < 0) y0 = 0;
    int y1 = cy + 2; if (y1 > 19) y1 = 19;
    int cnt = 0;
    for (int yy = y0; yy <= y1; yy++) {
        int rowb = yy * 20;
        int s = cellstart[rowb + x0];        // wave-uniform
        int e = cellstart[rowb + x1 + 1];    // cells in a row contiguous in pts
        for (int q = s + lane; q < e; q += 64) {   // coalesced lane-strided
            float4 pq = pts[q];
            float dot = p.x * pq.x + p.y * pq.y;
            float d2 = (p.z + pq.z) - 2.0f * dot;
            cnt += (d2 <= R2) ? 1 : 0;
        }
    }
#pragma unroll
    for (int off = 32; off > 0; off >>= 1) cnt += __shfl_xor(cnt, off, 64);
    if (lane == 0) dens[__float_as_int(p.w)] = cnt;
}

// ---------------- K5: fvar — bucket-major synchronized sweep ----------------
// RPW=4: 1024 blocks = 4/CU, all co-resident, phase-synced bucket sweep keeps
// the 2MB window L2-resident (R4: FETCH 207->74MB confirmed).
__global__ void __launch_bounds__(256) k_fvar(
    const float* __restrict__ x, const int* __restrict__ rp4,
    const int* __restrict__ cols, float* __restrict__ fvar, int N) {
    __shared__ float4 lds[4][8][64];   // 4 waves x 8 slots x 1KB = 32KB
    int wave = threadIdx.x >> 6;
    int lane = threadIdx.x & 63;
    int i0 = (blockIdx.x * 4 + wave) * RPW;
    const float4* xb = (const float4*)x;   // 64 float4 per row
    float4 acc[RPW];
#pragma unroll
    for (int r = 0; r < RPW; r++) acc[r] = make_float4(0.f, 0.f, 0.f, 0.f);

    for (int b = 0; b < NB; b++) {
#pragma unroll
        for (int r = 0; r < RPW; r++) {
            int s = rp4[(i0 + r) * NB + b];
            int e = rp4[(i0 + r) * NB + b + 1];
            for (int p0 = s; p0 < e; p0 += 64) {
                int m = e - p0; if (m > 64) m = 64;
                int idx = cols[p0 + (lane < m ? lane : m - 1)];
                for (int j = 0; j < m; j += 8) {
                    int nb2 = m - j; if (nb2 > 8) nb2 = 8;
#pragma unroll
                    for (int k = 0; k < 8; k++) {
                        if (k < nb2) {
                            int c = __shfl(idx, j + k, 64);
                            const float4* gp = xb + (size_t)c * 64 + lane;
                            __builtin_amdgcn_global_load_lds(
                                (const __attribute__((address_space(1))) void*)gp,
                                (__attribute__((address_space(3))) void*)(&lds[wave][k][0]),
                                16, 0, 0);
                        }
                    }
                    __builtin_amdgcn_s_waitcnt(0);   // drain the async row fetches
#pragma unroll
                    for (int k = 0; k < 8; k++) {
                        if (k < nb2) {
                            float4 v = lds[wave][k][lane];
                            acc[r].x += v.x; acc[r].y += v.y;
                            acc[r].z += v.z; acc[r].w += v.w;
                        }
                    }
                }
            }
        }
    }

#pragma unroll
    for (int r = 0; r < RPW; r++) {
        int i = i0 + r;
        float cnt = fmaxf((float)(rp4[(i + 1) * NB] - rp4[i * NB]), 1.0f);
        float4 xi = xb[(size_t)i * 64 + lane];
        float dx = xi.x - acc[r].x / cnt;
        float dy = xi.y - acc[r].y / cnt;
        float dz = xi.z - acc[r].z / cnt;
        float dw = xi.w - acc[r].w / cnt;
        float ss = dx * dx + dy * dy + dz * dz + dw * dw;
#pragma unroll
        for (int off = 32; off > 0; off >>= 1) ss += __shfl_xor(ss, off, 64);
        if (lane == 0) fvar[i] = sqrtf(ss);
    }
}

// ---------------- K5b: maxima reduction (deg, dens, fvar) ----------------
__global__ void __launch_bounds__(256) k_scal(
    const int* __restrict__ rp4, const int* __restrict__ dens,
    const float* __restrict__ fvar, int* __restrict__ scal, int N) {
    __shared__ int sd[4], sn[4];
    __shared__ float sf[4];
    int t = threadIdx.x;
    int g = blockIdx.x * 256 + t;
    int stride = 256 * gridDim.x;
    int md = 0, mn = 0;
    float mf = 0.f;
    for (int i = g; i < N; i += stride) {
        md = max(md, rp4[(i + 1) * NB] - rp4[i * NB]);
        mn = max(mn, dens[i]);
        mf = fmaxf(mf, fvar[i]);
    }
#pragma unroll
    for (int off = 32; off > 0; off >>= 1) {
        md = max(md, __shfl_xor(md, off, 64));
        mn = max(mn, __shfl_xor(mn, off, 64));
        mf = fmaxf(mf, __shfl_xor(mf, off, 64));
    }
    int w = t >> 6, l = t & 63;
    if (l == 0) { sd[w] = md; sn[w] = mn; sf[w] = mf; }
    __syncthreads();
    if (t == 0) {
#pragma unroll
        for (int k = 1; k < 4; k++) {
            md = max(md, sd[k]);
            mn = max(mn, sn[k]);
            mf = fmaxf(mf, sf[k]);
        }
        atomicMax(&scal[0], md);
        atomicMax(&scal[1], mn);
        atomicMax(&scal[2], __float_as_int(mf));   // nonneg float: int-max ok
    }
}

// ---------------- K6: tiny MLP ----------------
__global__ void __launch_bounds__(256) k_mlp(
    const float* __restrict__ w1, const float* __restrict__ b1,
    const float* __restrict__ w2, const float* __restrict__ b2,
    const int* __restrict__ rp4, const int* __restrict__ dens,
    const float* __restrict__ fvar, const int* __restrict__ scal,
    float* __restrict__ out, int N) {
    __shared__ float sh_h[HH];
    int j = threadIdx.x;
    float wv[HH];
#pragma unroll
    for (int l = 0; l < HH; l++) wv[l] = w2[l * H + j];
    float bj = b2[j];
    float maxdeg  = (float)scal[0] + EPSF;
    float maxdens = (float)(scal[1] - 1) + EPSF;
    float maxfv   = __int_as_float(scal[2]) + EPSF;
    float w1a = 0.f, w1b = 0.f, w1c = 0.f, b1j = 0.f;
    if (j < HH) { w1a = w1[j]; w1b = w1[HH + j]; w1c = w1[2 * HH + j]; b1j = b1[j]; }
    for (int i = blockIdx.x; i < N; i += gridDim.x) {
        float f0 = (float)(rp4[(i + 1) * NB] - rp4[i * NB]) / maxdeg;
        float f1 = (float)(dens[i] - 1) / maxdens;
        float f2 = fvar[i] / maxfv;
        if (j < HH) {
            float h = f0 * w1a + f1 * w1b + f2 * w1c + b1j;
            sh_h[j] = fmaxf(h, 0.0f);
        }
        __syncthreads();
        float acc = bj;
#pragma unroll
        for (int l = 0; l < HH; l++) acc = fmaf(sh_h[l], wv[l], acc);
        out[(size_t)i * H + j] = acc;
        __syncthreads();
    }
}

extern "C" void kernel_launch(void* const* d_in, const int* in_sizes, int n_in,
                              void* d_out, int out_size, void* d_ws, size_t ws_size,
                              hipStream_t stream) {
    const float* x      = (const float*)d_in[0];
    const int*   ei     = (const int*)d_in[1];
    const float* coords = (const float*)d_in[2];
    const float* w1     = (const float*)d_in[3];
    const float* b1     = (const float*)d_in[4];
    const float* w2     = (const float*)d_in[5];
    const float* b2     = (const float*)d_in[6];
    float* out = (float*)d_out;

    const int N = in_sizes[2] / 2;   // 16384
    const int E = in_sizes[1] / 2;   // 524288
    const int M = N * NB;            // 131072
    const int NBLK = M / 1024;       // 128 scan blocks
    const int* row = ei;
    const int* col = ei + E;

    // workspace layout (int32 elements; int4/float4 arrays 16B-aligned)
    int* ws        = (int*)d_ws;
    int* scal      = ws;                       // [4]     zeroed
    int* deg4      = ws + 4;                   // [M]     zeroed  (16B-aligned)
    int* cellcnt   = ws + 4 + M;               // [404]   zeroed  (400 used)
    int* rp4       = ws + 408 + M;             // [M+4]           (16B-aligned)
    int* cur4      = rp4 + M + 4;              // [M]             (16B-aligned)
    int* cellstart = cur4 + M;                 // [404]   (401 used)
    int* cellcur   = cellstart + 404;          // [400]
    int* dens_cnt  = cellcur + 400;            // [N]
    float* fvarp   = (float*)(dens_cnt + N);   // [N]
    int* bsum      = dens_cnt + 2 * N;         // [128]
    int* boff      = bsum + 128;               // [128]
    int* cols      = boff + 128;               // [E]
    float4* pts    = (float4*)(cols + E);      // [N]  (16B-aligned)

    hipMemsetAsync(ws, 0, (size_t)(408 + M) * sizeof(int), stream);

    int eb = (E + 255) / 256;
    k_degree<<<eb, 256, 0, stream>>>(row, col, deg4, E);
    k_bsum<<<NBLK, 256, 0, stream>>>(deg4, bsum);
    k_bscan<<<1, NBLK, 0, stream>>>(bsum, boff);
    k_scat<<<NBLK, 256, 0, stream>>>(deg4, boff, rp4, cur4, M);
    k_fill<<<eb, 256, 0, stream>>>(row, col, cur4, cols, E);

    k_cellcnt<<<N / 256, 256, 0, stream>>>(coords, cellcnt, N);
    k_cellscan<<<1, 512, 0, stream>>>(cellcnt, cellstart, cellcur);
    k_cellfill<<<N / 256, 256, 0, stream>>>(coords, cellcur, pts, N);
    k_dgrid<<<N / 4, 256, 0, stream>>>(pts, cellstart, dens_cnt, N);

    k_fvar<<<N / (4 * RPW), 256, 0, stream>>>(x, rp4, cols, fvarp, N);

    k_scal<<<64, 256, 0, stream>>>(rp4, dens_cnt, fvarp, scal, N);

    k_mlp<<<1024, 256, 0, stream>>>(w1, b1, w2, b2, rp4, dens_cnt, fvarp, scal,
                                    out, N);
}